// Round 2
// baseline (442.964 us; speedup 1.0000x reference)
//
#include <hip/hip_runtime.h>
#include <math.h>

// CSCR: B=32, C=256, H=W=56 (HW=3136). Output = concat(rgb_out, ir_out).
// Dual-dtype: runtime-detect bf16 vs fp32 inputs (flag in ws), matching output
// dtype assumed. Pipeline:
//  k_detect : 1 block — classify input dtype (bf16 N(0,1) has no |v|>1e3 when
//             read as bf16; fp32 misread as bf16 has ~46% weird halves)
//  k_sa     : per-(b,hw) channel mean+max both streams -> sigmoid -> sa32
//  k_sim    : per-(b,c) plane dot(sa,x) & sum(x^2), fp64 accum ->
//             sim = dot/max(||x||,1e-12). Per-batch ||sa|| factor dropped:
//             positive constant, preserves sign & ordering.
//  k_sort   : stable ascending rank-sort of 256 sims per (stream,b) + pos count
//             (NaN->-inf guard keeps ord a permutation -> no poison survives)
//  k_nmax   : n[stream] = max over batch of positive counts
//  k_gather : sorted-channel gather w/ insertion (extra = max of the two
//             first-sorted planes) * sa_sig; vectorized 16B I/O; src clamped.

#define CDIM   256
#define HWDIM  3136
#define CHW    (CDIM * HWDIM)        /* 802816 */
#define PAIRS  1568                  /* HWDIM/2 */

typedef unsigned short u16;
typedef unsigned int   u32;

__device__ __forceinline__ float bf2f(u32 u) { return __uint_as_float(u << 16); }
__device__ __forceinline__ u16  f2bf(float f) {
    u32 x = __float_as_uint(f);
    return (u16)((x + 0x7FFFu + ((x >> 16) & 1u)) >> 16);   // RNE
}
__device__ __forceinline__ u32 pack2(u32 u, float s0, float s1) {
    float a0 = __uint_as_float(u << 16);
    float a1 = __uint_as_float(u & 0xFFFF0000u);
    u32 lo = f2bf(a0 * s0), hi = f2bf(a1 * s1);
    return lo | (hi << 16);
}
__device__ __forceinline__ u32 maxpack2(u32 u, u32 w, float s0, float s1) {
    float a0 = __uint_as_float(u << 16), a1 = __uint_as_float(u & 0xFFFF0000u);
    float b0 = __uint_as_float(w << 16), b1 = __uint_as_float(w & 0xFFFF0000u);
    u32 lo = f2bf(fmaxf(a0, b0) * s0), hi = f2bf(fmaxf(a1, b1) * s1);
    return lo | (hi << 16);
}

// ---- dtype detect: flag=0 bf16, flag=1 fp32 ----
__global__ void k_detect(const u16* __restrict__ rgb, int* __restrict__ flag) {
    __shared__ int cs;
    if (threadIdx.x == 0) cs = 0;
    __syncthreads();
    int w = 0;
    for (int i = threadIdx.x; i < 8192; i += 256) {
        u16 u = rgb[i];
        int e = (u >> 7) & 0xFF;
        float v = bf2f((u32)u);
        if (e == 0xFF || fabsf(v) > 1e3f) w++;
    }
    atomicAdd(&cs, w);
    __syncthreads();
    if (threadIdx.x == 0) flag[0] = (cs > 256) ? 1 : 0;
}

// ---- k_sa: grid (25, 32), block 256 = 4 channel-groups x 64 pair-lanes.
// Each thread covers 2 consecutive hw positions (u32 / float2 loads). ----
__global__ __launch_bounds__(256) void k_sa(const void* __restrict__ rgb_,
                                            const void* __restrict__ ir_,
                                            const int* __restrict__ flag,
                                            float* __restrict__ sa32) {
    int b  = blockIdx.y;
    int g  = threadIdx.x >> 6;
    int pl = blockIdx.x * 64 + (threadIdx.x & 63);
    bool act = pl < PAIRS;
    int md = flag[0];

    double s0 = 0.0, s1 = 0.0;          // combined rgb+ir sums per position
    float m0r = -INFINITY, m1r = -INFINITY, m0i = -INFINITY, m1i = -INFINITY;
    if (act) {
        size_t base = (size_t)b * (CHW / 2) + pl;
        if (md == 0) {
            const u32* R = (const u32*)rgb_;
            const u32* I = (const u32*)ir_;
            for (int c = g; c < CDIM; c += 4) {
                u32 wr = R[base + (size_t)c * PAIRS];
                u32 wi = I[base + (size_t)c * PAIRS];
                float r0 = bf2f(wr & 0xFFFFu), r1 = bf2f(wr >> 16);
                float i0 = bf2f(wi & 0xFFFFu), i1 = bf2f(wi >> 16);
                s0 += (double)r0 + (double)i0;
                s1 += (double)r1 + (double)i1;
                m0r = fmaxf(m0r, r0); m1r = fmaxf(m1r, r1);
                m0i = fmaxf(m0i, i0); m1i = fmaxf(m1i, i1);
            }
        } else {
            const float2* R = (const float2*)rgb_;
            const float2* I = (const float2*)ir_;
            for (int c = g; c < CDIM; c += 4) {
                float2 vr = R[base + (size_t)c * PAIRS];
                float2 vi = I[base + (size_t)c * PAIRS];
                s0 += (double)vr.x + (double)vi.x;
                s1 += (double)vr.y + (double)vi.y;
                m0r = fmaxf(m0r, vr.x); m1r = fmaxf(m1r, vr.y);
                m0i = fmaxf(m0i, vi.x); m1i = fmaxf(m1i, vi.y);
            }
        }
    }
    __shared__ double sh_s0[256], sh_s1[256];
    __shared__ float sh_m0r[256], sh_m1r[256], sh_m0i[256], sh_m1i[256];
    int t = threadIdx.x;
    sh_s0[t] = s0; sh_s1[t] = s1;
    sh_m0r[t] = m0r; sh_m1r[t] = m1r; sh_m0i[t] = m0i; sh_m1i[t] = m1i;
    __syncthreads();
    if (g == 0 && act) {
        #pragma unroll
        for (int k = 1; k < 4; ++k) {
            int t2 = t + 64 * k;
            s0 += sh_s0[t2]; s1 += sh_s1[t2];
            m0r = fmaxf(m0r, sh_m0r[t2]); m1r = fmaxf(m1r, sh_m1r[t2]);
            m0i = fmaxf(m0i, sh_m0i[t2]); m1i = fmaxf(m1i, sh_m1i[t2]);
        }
        double sa0 = fmax(s0 * (1.0 / 256.0), (double)m0r + (double)m0i);
        double sa1 = fmax(s1 * (1.0 / 256.0), (double)m1r + (double)m1i);
        size_t o = (size_t)b * HWDIM + 2 * pl;
        sa32[o]     = (float)(1.0 / (1.0 + exp(-sa0)));
        sa32[o + 1] = (float)(1.0 / (1.0 + exp(-sa1)));
    }
}

// ---- k_sim: 4 planes/block (same batch), sa staged in LDS (12.5 KB) ----
__global__ __launch_bounds__(256) void k_sim(const void* __restrict__ rgb_,
                                             const void* __restrict__ ir_,
                                             const int* __restrict__ flag,
                                             const float* __restrict__ sa32,
                                             double* __restrict__ sims) {
    __shared__ float s_sa[HWDIM];
    int p0 = blockIdx.x * 4;
    int b  = (p0 >> 8) & 31;
    for (int i = threadIdx.x; i < HWDIM; i += 256)
        s_sa[i] = sa32[(size_t)b * HWDIM + i];
    __syncthreads();

    int wid = threadIdx.x >> 6, lane = threadIdx.x & 63;
    int p = p0 + wid;
    int stream = p >> 13;
    int md = flag[0];
    size_t base = (size_t)(p & 8191) * PAIRS;     // in 2-element units

    double ss = 0.0, dot = 0.0;
    if (md == 0) {
        const u32* x = (const u32*)(stream ? ir_ : rgb_);
        for (int j = lane; j < PAIRS; j += 64) {
            u32 w = x[base + j];
            double v0 = (double)bf2f(w & 0xFFFFu), v1 = (double)bf2f(w >> 16);
            ss  = fma(v0, v0, fma(v1, v1, ss));
            dot = fma((double)s_sa[2 * j], v0, fma((double)s_sa[2 * j + 1], v1, dot));
        }
    } else {
        const float2* x = (const float2*)(stream ? ir_ : rgb_);
        for (int j = lane; j < PAIRS; j += 64) {
            float2 w = x[base + j];
            double v0 = (double)w.x, v1 = (double)w.y;
            ss  = fma(v0, v0, fma(v1, v1, ss));
            dot = fma((double)s_sa[2 * j], v0, fma((double)s_sa[2 * j + 1], v1, dot));
        }
    }
    #pragma unroll
    for (int off = 32; off >= 1; off >>= 1) {
        ss  += __shfl_xor(ss,  off, 64);
        dot += __shfl_xor(dot, off, 64);
    }
    if (lane == 0) {
        double nrm = sqrt(ss);
        if (nrm < 1e-12) nrm = 1e-12;
        sims[p] = dot / nrm;
    }
}

// ---- k_sort: stable ascending argsort + positive count ----
__global__ __launch_bounds__(256) void k_sort(const double* __restrict__ sims,
                                              int* __restrict__ ord,
                                              int* __restrict__ cnt) {
    __shared__ double s[256];
    __shared__ int csum;
    int sb = blockIdx.x;
    int c  = threadIdx.x;
    double v = sims[sb * 256 + c];
    if (isnan(v)) v = -INFINITY;        // keep ranks a permutation, always
    s[c] = v;
    if (c == 0) csum = 0;
    __syncthreads();
    int rank = 0;
    #pragma unroll 8
    for (int j = 0; j < 256; ++j) {
        double u = s[j];
        rank += (u < v) || (u == v && j < c);
    }
    ord[sb * 256 + rank] = c;
    unsigned long long m = __ballot(v > 0.0);
    if ((c & 63) == 0) atomicAdd(&csum, (int)__popcll(m));
    __syncthreads();
    if (c == 0) cnt[sb] = csum;
}

__global__ void k_nmax(const int* __restrict__ cnt, int* __restrict__ nmax) {
    if (threadIdx.x == 0) {
        int n0 = 0, n1 = 0;
        for (int b = 0; b < 32; ++b) {
            n0 = max(n0, cnt[b]);
            n1 = max(n1, cnt[32 + b]);
        }
        nmax[0] = n0; nmax[1] = n1;
    }
}

// ---- k_gather: grid 16384 = stream*8192 + b*256 + c_out, block 256 ----
__global__ __launch_bounds__(256) void k_gather(const void* __restrict__ rgb_,
                                                const void* __restrict__ ir_,
                                                const int* __restrict__ flag,
                                                const float* __restrict__ sa32,
                                                const int* __restrict__ ord,
                                                const int* __restrict__ nmax,
                                                void* __restrict__ out_) {
    int sb = blockIdx.x;
    int stream = sb >> 13;
    int b  = (sb >> 8) & 31;
    int co = sb & 255;
    int md = flag[0];
    int n_self  = nmax[stream];
    int n_other = nmax[1 - stream];
    bool insert  = n_other > n_self;
    bool special = insert && (co == n_self);
    int obase = sb & ~255;

    const float*  sig = sa32 + (size_t)b * HWDIM;
    const float4* sg  = (const float4*)sig;

    if (!special) {
        int ci = co;
        if (insert && co > n_self) ci = co - 1;
        int src = ord[obase + ci] & 255;         // clamp: never OOB
        size_t pb = (size_t)(b * 256 + src) * HWDIM;
        if (md == 0) {
            const u16* x = stream ? (const u16*)ir_ : (const u16*)rgb_;
            const uint4* xin = (const uint4*)(x + pb);
            uint4* o = (uint4*)((u16*)out_ + (size_t)sb * HWDIM);
            for (int i = threadIdx.x; i < 392; i += 256) {
                uint4 u = xin[i];
                float4 s0 = sg[2 * i], s1 = sg[2 * i + 1];
                uint4 r;
                r.x = pack2(u.x, s0.x, s0.y);
                r.y = pack2(u.y, s0.z, s0.w);
                r.z = pack2(u.z, s1.x, s1.y);
                r.w = pack2(u.w, s1.z, s1.w);
                o[i] = r;
            }
        } else {
            const float* x = stream ? (const float*)ir_ : (const float*)rgb_;
            const float4* xin = (const float4*)(x + pb);
            float4* o = (float4*)((float*)out_ + (size_t)sb * HWDIM);
            for (int i = threadIdx.x; i < 784; i += 256) {
                float4 v = xin[i], s = sg[i];
                o[i] = make_float4(v.x * s.x, v.y * s.y, v.z * s.z, v.w * s.w);
            }
        }
    } else {
        int src_r = ord[b * 256] & 255;
        int src_i = ord[8192 + b * 256] & 255;
        size_t pr = (size_t)(b * 256 + src_r) * HWDIM;
        size_t pi = (size_t)(b * 256 + src_i) * HWDIM;
        if (md == 0) {
            const uint4* xr = (const uint4*)((const u16*)rgb_ + pr);
            const uint4* xi = (const uint4*)((const u16*)ir_  + pi);
            uint4* o = (uint4*)((u16*)out_ + (size_t)sb * HWDIM);
            for (int i = threadIdx.x; i < 392; i += 256) {
                uint4 u = xr[i], w = xi[i];
                float4 s0 = sg[2 * i], s1 = sg[2 * i + 1];
                uint4 r;
                r.x = maxpack2(u.x, w.x, s0.x, s0.y);
                r.y = maxpack2(u.y, w.y, s0.z, s0.w);
                r.z = maxpack2(u.z, w.z, s1.x, s1.y);
                r.w = maxpack2(u.w, w.w, s1.z, s1.w);
                o[i] = r;
            }
        } else {
            const float4* xr = (const float4*)((const float*)rgb_ + pr);
            const float4* xi = (const float4*)((const float*)ir_  + pi);
            float4* o = (float4*)((float*)out_ + (size_t)sb * HWDIM);
            for (int i = threadIdx.x; i < 784; i += 256) {
                float4 u = xr[i], w = xi[i], s = sg[i];
                o[i] = make_float4(fmaxf(u.x, w.x) * s.x, fmaxf(u.y, w.y) * s.y,
                                   fmaxf(u.z, w.z) * s.z, fmaxf(u.w, w.w) * s.w);
            }
        }
    }
}

extern "C" void kernel_launch(void* const* d_in, const int* in_sizes, int n_in,
                              void* d_out, int out_size, void* d_ws, size_t ws_size,
                              hipStream_t stream) {
    const void* rgb = d_in[0];
    const void* ir  = d_in[1];

    char* ws = (char*)d_ws;
    int*    flg  = (int*)   ws;              // @ 0       (4 B)
    float*  sa32 = (float*) (ws + 1024);     // @ 1024    (401408 B)
    double* sims = (double*)(ws + 402432);   // @ 402432  (131072 B)
    int*    ord  = (int*)   (ws + 533504);   // @ 533504  (65536 B)
    int*    cnt  = (int*)   (ws + 599040);   // @ 599040  (256 B)
    int*    nmx  = (int*)   (ws + 599296);   // @ 599296  (8 B)   total < 600 KB

    k_detect<<<1,            256, 0, stream>>>((const u16*)rgb, flg);
    k_sa    <<<dim3(25, 32), 256, 0, stream>>>(rgb, ir, flg, sa32);
    k_sim   <<<4096,         256, 0, stream>>>(rgb, ir, flg, sa32, sims);
    k_sort  <<<64,           256, 0, stream>>>(sims, ord, cnt);
    k_nmax  <<<1,             64, 0, stream>>>(cnt, nmx);
    k_gather<<<16384,        256, 0, stream>>>(rgb, ir, flg, sa32, ord, nmx, d_out);
}